// Round 4
// baseline (2545.773 us; speedup 1.0000x reference)
//
#include <hip/hip_runtime.h>

#define DM 256
#define NH 4
#define HD 64
#define DEG 32
#define LQ 33
#define DOUT 128
#define NTHREADS 256

typedef __attribute__((ext_vector_type(8))) short bf8v;   // 8 bf16 = 4 VGPRs (MFMA A/B frag)
typedef __attribute__((ext_vector_type(4))) float f4v;    // MFMA C/D frag

__device__ __forceinline__ float b2f(unsigned short u){ union{unsigned int i;float f;}v; v.i=((unsigned int)u)<<16; return v.f; }
__device__ __forceinline__ unsigned short f2b(float f){
  union{float f;unsigned int i;}v; v.f=f;
  unsigned int r=v.i+0x7FFFu+((v.i>>16)&1u);
  return (unsigned short)(r>>16);
}
__device__ __forceinline__ float wred(float x){
  #pragma unroll
  for (int o=32;o>=1;o>>=1) x += __shfl_xor(x,o,64);
  return x;
}

// XOR swizzle for [R][256] bf16 LDS tiles read as ds_read_b128 A-fragments
__device__ __forceinline__ int swz(int r, int c){ return r*DM + (((c>>3) ^ (r&7))<<3) + (c&7); }
// XOR swizzle for [R][64] bf16 tiles (Q/P, K, VT, AO)
__device__ __forceinline__ int swzV(int r, int c){ return r*HD + (((c>>3) ^ (r&7))<<3) + (c&7); }

template<bool BF>
__device__ __forceinline__ bf8v wfrag(const float* Wf, const unsigned short* Wb, int row, int e){
  if constexpr (BF) {
    return *(const bf8v*)(Wb + (size_t)row*DM + e);
  } else {
    const float* p = Wf + (size_t)row*DM + e;
    const float4 a = *(const float4*)p;
    const float4 b = *(const float4*)(p+4);
    bf8v r;
    r[0]=(short)(__float_as_uint(a.x)>>16); r[1]=(short)(__float_as_uint(a.y)>>16);
    r[2]=(short)(__float_as_uint(a.z)>>16); r[3]=(short)(__float_as_uint(a.w)>>16);
    r[4]=(short)(__float_as_uint(b.x)>>16); r[5]=(short)(__float_as_uint(b.y)>>16);
    r[6]=(short)(__float_as_uint(b.z)>>16); r[7]=(short)(__float_as_uint(b.w)>>16);
    return r;
  }
}

__device__ __forceinline__ f4v mfma16(bf8v a, bf8v b, f4v c){
  return __builtin_amdgcn_mfma_f32_16x16x32_bf16(a, b, c, 0, 0, 0);
}

// U region (u16 offsets). Q/P overlay; X-staging and Mid use the whole region.
#define U_Q  0       // [48][64] swzV  (P overlays after scores)
#define U_K  3072    // [48][64] swzV
#define U_VT 6144    // [64][64] swzV   VT[d][key]; keys 48..63 stay zero
#define U_AO 10240   // [48][64] swzV
#define U_SZ 13312

template<bool WBF16>
__global__ __launch_bounds__(NTHREADS, 3) void smtp_center(
    const float* __restrict__ H,
    const int* __restrict__ dstE,
    const int* __restrict__ centers,
    const float* __restrict__ target,
    const float* __restrict__ ln_in_w,
    const float* __restrict__ ln1_w,
    const float* __restrict__ ln2_w,
    const float* __restrict__ w_qkv,
    const float* __restrict__ b_qkv,
    const float* __restrict__ w_o,
    const float* __restrict__ b_o,
    const float* __restrict__ w_gate,
    const float* __restrict__ w_up,
    const float* __restrict__ w_down,
    const float* __restrict__ w_head,
    const float* __restrict__ b_head,
    const unsigned short* __restrict__ wb,
    float* __restrict__ partial)
{
  __shared__ __align__(16) unsigned short sN[48*DM];   // xn / xn2 / Z, swizzled
  __shared__ __align__(16) unsigned short U[U_SZ];
  __shared__ float sRowSum[48*4];
  __shared__ int sIdx[48];
  __shared__ float sRed[4];

  const unsigned short* wbQKV = wb;
  const unsigned short* wbO   = wb + 196608;
  const unsigned short* wbG   = wb + 262144;
  const unsigned short* wbU   = wb + 327680;
  const unsigned short* wbD   = wb + 393216;
  const unsigned short* wbH   = wb + 458752;

  const int tid  = threadIdx.x;
  const int lane = tid & 63;
  const int wave = tid >> 6;
  const int bid  = blockIdx.x;
  const int l15  = lane & 15;
  const int l16  = (lane >> 4) * 8;
  const int rsub = (lane >> 4) * 4;

  // P0: star indices
  if (tid < LQ) {
    int ctr = centers[bid];
    sIdx[tid] = (tid == 0) ? ctr : dstE[(size_t)ctr*DEG + (tid-1)];
  }
  __syncthreads();

  // P1: gather + rmsnorm(ln_in) -> X staged in U [48][256] swz; rmsnorm(ln1) -> sN swz
  for (int r = wave; r < LQ; r += 4) {
    const float4 x4 = ((const float4*)(H + (size_t)sIdx[r]*DM))[lane];
    float ss = x4.x*x4.x + x4.y*x4.y + x4.z*x4.z + x4.w*x4.w;
    ss = wred(ss);
    const float rs = rsqrtf(ss*(1.f/DM) + 1e-6f);
    const float4 wi = ((const float4*)ln_in_w)[lane];
    const float xv0 = x4.x*rs*wi.x, xv1 = x4.y*rs*wi.y, xv2 = x4.z*rs*wi.z, xv3 = x4.w*rs*wi.w;
    ushort4 xb; xb.x=f2b(xv0); xb.y=f2b(xv1); xb.z=f2b(xv2); xb.w=f2b(xv3);
    *(ushort4*)(U + swz(r, lane*4)) = xb;
    float s2 = xv0*xv0 + xv1*xv1 + xv2*xv2 + xv3*xv3;
    s2 = wred(s2);
    const float rs2 = rsqrtf(s2*(1.f/DM) + 1e-6f);
    const float4 w1 = ((const float4*)ln1_w)[lane];
    ushort4 yb; yb.x=f2b(xv0*rs2*w1.x); yb.y=f2b(xv1*rs2*w1.y); yb.z=f2b(xv2*rs2*w1.z); yb.w=f2b(xv3*rs2*w1.w);
    *(ushort4*)(sN + swz(r, lane*4)) = yb;
  }
  {
    ushort4 z4; z4.x=0; z4.y=0; z4.z=0; z4.w=0;
    for (int r = LQ + wave; r < 48; r += 4) {
      *(ushort4*)(U  + swz(r, lane*4)) = z4;   // X pad rows (feed regX)
      ((ushort4*)(sN + r*DM))[lane]    = z4;   // zeros are swizzle-invariant
    }
  }
  __syncthreads();

  // P1b: residual X -> per-wave C-fragments regX[m][t4]; fold b_o in once.
  f4v regX[3][4];
  {
    #pragma unroll
    for (int t4 = 0; t4 < 4; ++t4) {
      const int col = wave*64 + t4*16 + l15;
      const float bo = b_o[col];
      #pragma unroll
      for (int m = 0; m < 3; ++m)
        #pragma unroll
        for (int j = 0; j < 4; ++j)
          regX[m][t4][j] = b2f(U[swz(m*16 + rsub + j, col)]) + bo;
    }
  }
  __syncthreads();   // U free for QKV outputs

  // VT pad keys 48..63 = 0 (once; disjoint from QKV's key 0..47 writes)
  if (tid < 128) {
    const int d = tid >> 1;
    const int key = 48 + (tid & 1)*8;
    *(uint4*)&U[U_VT + swzV(d, key)] = make_uint4(0,0,0,0);
  }

  // P2: per head: QKV | bar | scores+softmax+P | bar | PV+AO | bar | WO (no bar; disjoint from next QKV)
  for (int h = 0; h < NH; ++h) {
    // 2a QKV: M=48 x N=192, K=256; 3 N-tiles/wave
    #pragma unroll
    for (int t3 = 0; t3 < 3; ++t3) {
      const int t = wave*3 + t3;
      const int col = t*16 + l15;
      const int sect = t >> 2;             // 0=Q 1=K 2=V
      const int c = col & 63;
      const int wrow = sect*DM + h*HD + c;
      const float bias = b_qkv[wrow];
      f4v acc[3];
      acc[0] = (f4v){bias,bias,bias,bias}; acc[1] = acc[0]; acc[2] = acc[0];
      #pragma unroll
      for (int k = 0; k < 8; ++k) {
        const bf8v b = wfrag<WBF16>(w_qkv, wbQKV, wrow, k*32 + l16);
        #pragma unroll
        for (int m = 0; m < 3; ++m) {
          const bf8v a = *(const bf8v*)(sN + swz(m*16 + l15, k*32 + l16));
          acc[m] = mfma16(a, b, acc[m]);
        }
      }
      if (sect == 2) {
        #pragma unroll
        for (int m = 0; m < 3; ++m)
          #pragma unroll
          for (int j = 0; j < 4; ++j)
            U[U_VT + swzV(c, m*16 + rsub + j)] = f2b(acc[m][j]);
      } else {
        unsigned short* dstb = U + (sect ? U_K : U_Q);
        #pragma unroll
        for (int m = 0; m < 3; ++m)
          #pragma unroll
          for (int j = 0; j < 4; ++j)
            dstb[swzV(m*16 + rsub + j, c)] = f2b(acc[m][j]);
      }
    }
    __syncthreads();

    // 2b scores (waves 0-2) + in-register softmax + P write (own Q rows only)
    if (wave < 3) {
      f4v s3[3];
      s3[0] = (f4v){0.f,0.f,0.f,0.f}; s3[1] = s3[0]; s3[2] = s3[0];
      #pragma unroll
      for (int kk = 0; kk < 2; ++kk) {
        const bf8v a = *(const bf8v*)(U + U_Q + swzV(wave*16 + l15, kk*32 + l16));
        #pragma unroll
        for (int nk = 0; nk < 3; ++nk) {
          const bf8v bb = *(const bf8v*)(U + U_K + swzV(nk*16 + l15, kk*32 + l16));
          s3[nk] = mfma16(a, bb, s3[nk]);
        }
      }
      #pragma unroll
      for (int j = 0; j < 4; ++j) {
        const float v0 = s3[0][j]*0.125f;
        const float v1 = s3[1][j]*0.125f;
        const float v2 = (l15 >= 1) ? -INFINITY : s3[2][j]*0.125f;  // keys 33..47 masked
        float mx = fmaxf(fmaxf(v0, v1), v2);
        mx = fmaxf(mx, __shfl_xor(mx, 1, 64));
        mx = fmaxf(mx, __shfl_xor(mx, 2, 64));
        mx = fmaxf(mx, __shfl_xor(mx, 4, 64));
        mx = fmaxf(mx, __shfl_xor(mx, 8, 64));
        const float e0 = __expf(v0 - mx), e1 = __expf(v1 - mx), e2 = __expf(v2 - mx);
        float den = e0 + e1 + e2;
        den += __shfl_xor(den, 1, 64);
        den += __shfl_xor(den, 2, 64);
        den += __shfl_xor(den, 4, 64);
        den += __shfl_xor(den, 8, 64);
        const float rn = 1.f / den;
        const int row = wave*16 + rsub + j;
        U[U_Q + swzV(row, 0*16 + l15)] = f2b(e0 * rn);
        U[U_Q + swzV(row, 1*16 + l15)] = f2b(e1 * rn);
        U[U_Q + swzV(row, 2*16 + l15)] = f2b(e2 * rn);
      }
    }
    __syncthreads();

    // 2c PV: O = P @ V, wave = d-tile; K=64 (keys 48..63: P garbage x VT zero = 0)
    {
      f4v o4[3];
      o4[0] = (f4v){0.f,0.f,0.f,0.f}; o4[1] = o4[0]; o4[2] = o4[0];
      #pragma unroll
      for (int kk = 0; kk < 2; ++kk) {
        const bf8v bb = *(const bf8v*)(U + U_VT + swzV(wave*16 + l15, kk*32 + l16));
        #pragma unroll
        for (int mq = 0; mq < 3; ++mq) {
          const bf8v a = *(const bf8v*)(U + U_Q + swzV(mq*16 + l15, kk*32 + l16));
          o4[mq] = mfma16(a, bb, o4[mq]);
        }
      }
      #pragma unroll
      for (int mq = 0; mq < 3; ++mq)
        #pragma unroll
        for (int j = 0; j < 4; ++j)
          U[U_AO + swzV(mq*16 + rsub + j, wave*16 + l15)] = f2b(o4[mq][j]);
    }
    __syncthreads();

    // 2d WO: regX += AO_h @ w_o[:, h*64:(h+1)*64]^T  (C-in/out = regX, no LDS for X)
    #pragma unroll
    for (int t4 = 0; t4 < 4; ++t4) {
      const int col = wave*64 + t4*16 + l15;
      #pragma unroll
      for (int k = 0; k < 2; ++k) {
        const bf8v b = wfrag<WBF16>(w_o, wbO, col, h*HD + k*32 + l16);
        #pragma unroll
        for (int m = 0; m < 3; ++m) {
          const bf8v a = *(const bf8v*)(U + U_AO + swzV(m*16 + l15, k*32 + l16));
          regX[m][t4] = mfma16(a, b, regX[m][t4]);
        }
      }
    }
    // no barrier: WO reads AO only; next QKV writes Q/K/VT (disjoint) — except last head
  }

  // P3: rmsnorm(X, ln2) from fragments. Row partials -> sRowSum, then xn2 -> sN swz
  #pragma unroll
  for (int m = 0; m < 3; ++m)
    #pragma unroll
    for (int j = 0; j < 4; ++j) {
      float p = 0.f;
      #pragma unroll
      for (int t4 = 0; t4 < 4; ++t4) p += regX[m][t4][j]*regX[m][t4][j];
      p += __shfl_xor(p, 1, 64);
      p += __shfl_xor(p, 2, 64);
      p += __shfl_xor(p, 4, 64);
      p += __shfl_xor(p, 8, 64);
      if (l15 == 0) sRowSum[(m*16 + rsub + j)*4 + wave] = p;
    }
  __syncthreads();
  {
    #pragma unroll
    for (int t4 = 0; t4 < 4; ++t4) {
      const int col = wave*64 + t4*16 + l15;
      const float w2 = ln2_w[col];
      #pragma unroll
      for (int m = 0; m < 3; ++m)
        #pragma unroll
        for (int j = 0; j < 4; ++j) {
          const int row = m*16 + rsub + j;
          const float tot = sRowSum[row*4+0] + sRowSum[row*4+1] + sRowSum[row*4+2] + sRowSum[row*4+3];
          const float rs = rsqrtf(tot*(1.f/DM) + 1e-6f);
          sN[swz(row, col)] = f2b(regX[m][t4][j] * rs * w2);
        }
    }
  }
  __syncthreads();

  // P4: gate/up GEMM -> mid = silu(g)*u -> U swz [48][256]
  #pragma unroll
  for (int t4 = 0; t4 < 4; ++t4) {
    const int col = wave*64 + t4*16 + l15;
    f4v aG[3], aU[3];
    #pragma unroll
    for (int m = 0; m < 3; ++m) { aG[m] = (f4v){0.f,0.f,0.f,0.f}; aU[m] = aG[m]; }
    #pragma unroll
    for (int k = 0; k < 8; ++k) {
      const bf8v bg = wfrag<WBF16>(w_gate, wbG, col, k*32 + l16);
      const bf8v bu = wfrag<WBF16>(w_up,   wbU, col, k*32 + l16);
      #pragma unroll
      for (int m = 0; m < 3; ++m) {
        const bf8v a = *(const bf8v*)(sN + swz(m*16 + l15, k*32 + l16));
        aG[m] = mfma16(a, bg, aG[m]);
        aU[m] = mfma16(a, bu, aU[m]);
      }
    }
    #pragma unroll
    for (int m = 0; m < 3; ++m)
      #pragma unroll
      for (int j = 0; j < 4; ++j) {
        const float g = aG[m][j];
        const float v = (g / (1.f + __expf(-g))) * aU[m][j];
        U[swz(m*16 + rsub + j, col)] = f2b(v);
      }
  }
  __syncthreads();

  // P5: Z = X + mid @ w_down^T  (C-in = regX) -> sN swz
  #pragma unroll
  for (int t4 = 0; t4 < 4; ++t4) {
    const int col = wave*64 + t4*16 + l15;
    f4v acc = regX[0][t4];
    f4v acc1 = regX[1][t4];
    f4v acc2 = regX[2][t4];
    #pragma unroll
    for (int k = 0; k < 8; ++k) {
      const bf8v b = wfrag<WBF16>(w_down, wbD, col, k*32 + l16);
      acc  = mfma16(*(const bf8v*)(U + swz(0*16 + l15, k*32 + l16)), b, acc);
      acc1 = mfma16(*(const bf8v*)(U + swz(1*16 + l15, k*32 + l16)), b, acc1);
      acc2 = mfma16(*(const bf8v*)(U + swz(2*16 + l15, k*32 + l16)), b, acc2);
    }
    #pragma unroll
    for (int j = 0; j < 4; ++j) {
      sN[swz(0*16 + rsub + j, col)] = f2b(acc[j]);
      sN[swz(1*16 + rsub + j, col)] = f2b(acc1[j]);
      sN[swz(2*16 + rsub + j, col)] = f2b(acc2[j]);
    }
  }
  __syncthreads();

  // P6: head GEMM on rows 1..32 + MSE vs gathered targets
  float lsum = 0.f;
  #pragma unroll
  for (int t2 = 0; t2 < 2; ++t2) {
    const int col = (wave*2 + t2)*16 + l15;   // 0..127
    const float bh = b_head[col];
    f4v acc[2];
    acc[0] = (f4v){bh,bh,bh,bh}; acc[1] = acc[0];
    #pragma unroll
    for (int k = 0; k < 8; ++k) {
      const bf8v b = wfrag<WBF16>(w_head, wbH, col, k*32 + l16);
      #pragma unroll
      for (int m = 0; m < 2; ++m) {
        const bf8v a = *(const bf8v*)(sN + swz(1 + m*16 + l15, k*32 + l16));
        acc[m] = mfma16(a, b, acc[m]);
      }
    }
    #pragma unroll
    for (int m = 0; m < 2; ++m)
      #pragma unroll
      for (int j = 0; j < 4; ++j) {
        const int row = 1 + m*16 + rsub + j;          // 1..32
        const float tv = target[(size_t)sIdx[row]*DOUT + col];
        const float d = acc[m][j] - tv;
        lsum += d*d;
      }
  }
  lsum = wred(lsum);
  if (lane == 0) sRed[wave] = lsum;
  __syncthreads();
  if (tid == 0)
    partial[bid] = (sRed[0]+sRed[1]+sRed[2]+sRed[3]) * (1.f/(DEG*DOUT));
}

// one-time (per launch) f32 -> bf16 weight conversion into d_ws
__global__ void cvt_w(const float* __restrict__ qkv, const float* __restrict__ o,
                      const float* __restrict__ g, const float* __restrict__ u,
                      const float* __restrict__ dn, const float* __restrict__ hd,
                      unsigned short* __restrict__ out)
{
  const int i = blockIdx.x*NTHREADS + threadIdx.x;
  const int e = i*2;
  if (e >= 491520) return;
  const float* src; int off;
  if      (e < 196608){ src=qkv; off=e; }
  else if (e < 262144){ src=o;  off=e-196608; }
  else if (e < 327680){ src=g;  off=e-262144; }
  else if (e < 393216){ src=u;  off=e-327680; }
  else if (e < 458752){ src=dn; off=e-393216; }
  else                { src=hd; off=e-458752; }
  const float2 v = *(const float2*)(src + off);
  const unsigned int pk = (unsigned int)f2b(v.x) | ((unsigned int)f2b(v.y) << 16);
  *(unsigned int*)(out + e) = pk;
}

__global__ void smtp_reduce(const float* __restrict__ partial, int B, float* __restrict__ out)
{
  __shared__ float sRed[4];
  const int tid = threadIdx.x;
  float s = 0.f;
  for (int i = tid; i < B; i += NTHREADS) s += partial[i];
  s = wred(s);
  if ((tid & 63) == 0) sRed[tid>>6] = s;
  __syncthreads();
  if (tid == 0) out[0] = (sRed[0]+sRed[1]+sRed[2]+sRed[3]) / (float)B;
}

extern "C" void kernel_launch(void* const* d_in, const int* in_sizes, int n_in,
                              void* d_out, int out_size, void* d_ws, size_t ws_size,
                              hipStream_t stream) {
  const float* H        = (const float*)d_in[0];
  const int*   edge     = (const int*)d_in[1];
  const int*   centers  = (const int*)d_in[2];
  const float* target   = (const float*)d_in[3];
  const float* ln_in_w  = (const float*)d_in[5];
  const float* ln1_w    = (const float*)d_in[6];
  const float* ln2_w    = (const float*)d_in[7];
  const float* w_qkv    = (const float*)d_in[8];
  const float* b_qkv    = (const float*)d_in[9];
  const float* w_o      = (const float*)d_in[10];
  const float* b_o      = (const float*)d_in[11];
  const float* w_gate   = (const float*)d_in[12];
  const float* w_up     = (const float*)d_in[13];
  const float* w_down   = (const float*)d_in[14];
  const float* w_head   = (const float*)d_in[15];
  const float* b_head   = (const float*)d_in[16];

  const int B = in_sizes[2];
  const int E = in_sizes[1] / 2;
  const int* dstE = edge + E;

  const size_t WB_ELEMS = 491520;
  const size_t NEED = WB_ELEMS*2 + (size_t)B*4;
  const bool useBf = (ws_size >= NEED);

  if (useBf) {
    unsigned short* wb = (unsigned short*)d_ws;
    float* partial = (float*)((char*)d_ws + WB_ELEMS*2);
    cvt_w<<<960, NTHREADS, 0, stream>>>(w_qkv, w_o, w_gate, w_up, w_down, w_head, wb);
    smtp_center<true><<<B, NTHREADS, 0, stream>>>(H, dstE, centers, target, ln_in_w, ln1_w, ln2_w,
        w_qkv, b_qkv, w_o, b_o, w_gate, w_up, w_down, w_head, b_head, wb, partial);
    smtp_reduce<<<1, NTHREADS, 0, stream>>>(partial, B, (float*)d_out);
  } else {
    float* partial = (float*)d_ws;
    smtp_center<false><<<B, NTHREADS, 0, stream>>>(H, dstE, centers, target, ln_in_w, ln1_w, ln2_w,
        w_qkv, b_qkv, w_o, b_o, w_gate, w_up, w_down, w_head, b_head, (const unsigned short*)d_ws, partial);
    smtp_reduce<<<1, NTHREADS, 0, stream>>>(partial, B, (float*)d_out);
  }
}

// Round 5
// 1877.779 us; speedup vs baseline: 1.3557x; 1.3557x over previous
//
#include <hip/hip_runtime.h>

#define DM 256
#define NH 4
#define HD 64
#define DEG 32
#define LQ 33
#define DOUT 128
#define NTHREADS 256

typedef __attribute__((ext_vector_type(8))) short bf8v;   // 8 bf16 = 4 VGPRs (MFMA A/B frag)
typedef __attribute__((ext_vector_type(4))) float f4v;    // MFMA C/D frag

__device__ __forceinline__ float b2f(unsigned short u){ union{unsigned int i;float f;}v; v.i=((unsigned int)u)<<16; return v.f; }
__device__ __forceinline__ unsigned short f2b(float f){
  union{float f;unsigned int i;}v; v.f=f;
  unsigned int r=v.i+0x7FFFu+((v.i>>16)&1u);
  return (unsigned short)(r>>16);
}
__device__ __forceinline__ float wred(float x){
  #pragma unroll
  for (int o=32;o>=1;o>>=1) x += __shfl_xor(x,o,64);
  return x;
}

// XOR swizzle for [R][256] bf16 LDS tiles read as ds_read_b128 A-fragments
__device__ __forceinline__ int swz(int r, int c){ return r*DM + (((c>>3) ^ (r&7))<<3) + (c&7); }
// XOR swizzle for [R][64] bf16 tiles (Q/P, K, VT, AO)
__device__ __forceinline__ int swzV(int r, int c){ return r*HD + (((c>>3) ^ (r&7))<<3) + (c&7); }

template<bool BF>
__device__ __forceinline__ bf8v wfrag(const float* Wf, const unsigned short* Wb, int row, int e){
  if constexpr (BF) {
    return *(const bf8v*)(Wb + (size_t)row*DM + e);
  } else {
    const float* p = Wf + (size_t)row*DM + e;
    const float4 a = *(const float4*)p;
    const float4 b = *(const float4*)(p+4);
    bf8v r;
    r[0]=(short)(__float_as_uint(a.x)>>16); r[1]=(short)(__float_as_uint(a.y)>>16);
    r[2]=(short)(__float_as_uint(a.z)>>16); r[3]=(short)(__float_as_uint(a.w)>>16);
    r[4]=(short)(__float_as_uint(b.x)>>16); r[5]=(short)(__float_as_uint(b.y)>>16);
    r[6]=(short)(__float_as_uint(b.z)>>16); r[7]=(short)(__float_as_uint(b.w)>>16);
    return r;
  }
}

__device__ __forceinline__ f4v mfma16(bf8v a, bf8v b, f4v c){
  return __builtin_amdgcn_mfma_f32_16x16x32_bf16(a, b, c, 0, 0, 0);
}

// U region (u16 offsets). Q/P overlay; X-staging and Mid use the whole region.
#define U_Q  0       // [48][64] swzV  (P overlays after scores)
#define U_K  3072    // [48][64] swzV
#define U_VT 6144    // [64][64] swzV   VT[d][key]; keys 48..63 stay zero
#define U_AO 10240   // [48][64] swzV
#define U_SZ 13312

template<bool WBF16>
__global__ __launch_bounds__(NTHREADS, 2) void smtp_center(
    const float* __restrict__ H,
    const int* __restrict__ dstE,
    const int* __restrict__ centers,
    const float* __restrict__ target,
    const float* __restrict__ ln_in_w,
    const float* __restrict__ ln1_w,
    const float* __restrict__ ln2_w,
    const float* __restrict__ w_qkv,
    const float* __restrict__ b_qkv,
    const float* __restrict__ w_o,
    const float* __restrict__ b_o,
    const float* __restrict__ w_gate,
    const float* __restrict__ w_up,
    const float* __restrict__ w_down,
    const float* __restrict__ w_head,
    const float* __restrict__ b_head,
    const unsigned short* __restrict__ wb,
    float* __restrict__ partial)
{
  __shared__ __align__(16) unsigned short sN[48*DM];   // xn / xn2 / Z, swizzled
  __shared__ __align__(16) unsigned short U[U_SZ];
  __shared__ float sRowSum[48*4];
  __shared__ int sIdx[48];
  __shared__ float sRed[4];

  const unsigned short* wbQKV = wb;
  const unsigned short* wbO   = wb + 196608;
  const unsigned short* wbG   = wb + 262144;
  const unsigned short* wbU   = wb + 327680;
  const unsigned short* wbD   = wb + 393216;
  const unsigned short* wbH   = wb + 458752;

  const int tid  = threadIdx.x;
  const int lane = tid & 63;
  const int wave = tid >> 6;
  const int bid  = blockIdx.x;
  const int l15  = lane & 15;
  const int l16  = (lane >> 4) * 8;
  const int rsub = (lane >> 4) * 4;

  // P0: star indices
  if (tid < LQ) {
    int ctr = centers[bid];
    sIdx[tid] = (tid == 0) ? ctr : dstE[(size_t)ctr*DEG + (tid-1)];
  }
  __syncthreads();

  // P1: gather + rmsnorm(ln_in) -> X staged in U [48][256] swz; rmsnorm(ln1) -> sN swz
  for (int r = wave; r < LQ; r += 4) {
    const float4 x4 = ((const float4*)(H + (size_t)sIdx[r]*DM))[lane];
    float ss = x4.x*x4.x + x4.y*x4.y + x4.z*x4.z + x4.w*x4.w;
    ss = wred(ss);
    const float rs = rsqrtf(ss*(1.f/DM) + 1e-6f);
    const float4 wi = ((const float4*)ln_in_w)[lane];
    const float xv0 = x4.x*rs*wi.x, xv1 = x4.y*rs*wi.y, xv2 = x4.z*rs*wi.z, xv3 = x4.w*rs*wi.w;
    ushort4 xb; xb.x=f2b(xv0); xb.y=f2b(xv1); xb.z=f2b(xv2); xb.w=f2b(xv3);
    *(ushort4*)(U + swz(r, lane*4)) = xb;
    float s2 = xv0*xv0 + xv1*xv1 + xv2*xv2 + xv3*xv3;
    s2 = wred(s2);
    const float rs2 = rsqrtf(s2*(1.f/DM) + 1e-6f);
    const float4 w1 = ((const float4*)ln1_w)[lane];
    ushort4 yb; yb.x=f2b(xv0*rs2*w1.x); yb.y=f2b(xv1*rs2*w1.y); yb.z=f2b(xv2*rs2*w1.z); yb.w=f2b(xv3*rs2*w1.w);
    *(ushort4*)(sN + swz(r, lane*4)) = yb;
  }
  {
    ushort4 z4; z4.x=0; z4.y=0; z4.z=0; z4.w=0;
    for (int r = LQ + wave; r < 48; r += 4) {
      *(ushort4*)(U  + swz(r, lane*4)) = z4;   // X pad rows (feed regX)
      ((ushort4*)(sN + r*DM))[lane]    = z4;   // zeros are swizzle-invariant
    }
  }
  __syncthreads();

  // P1b: residual X -> per-wave C-fragments regX[m][t4]; fold b_o in once.
  f4v regX[3][4];
  {
    #pragma unroll
    for (int t4 = 0; t4 < 4; ++t4) {
      const int col = wave*64 + t4*16 + l15;
      const float bo = b_o[col];
      #pragma unroll
      for (int m = 0; m < 3; ++m)
        #pragma unroll
        for (int j = 0; j < 4; ++j)
          regX[m][t4][j] = b2f(U[swz(m*16 + rsub + j, col)]) + bo;
    }
  }
  __syncthreads();   // U free for QKV outputs

  // VT pad keys 48..63 = 0 (once; disjoint from QKV's key 0..47 writes)
  if (tid < 128) {
    const int d = tid >> 1;
    const int key = 48 + (tid & 1)*8;
    *(uint4*)&U[U_VT + swzV(d, key)] = make_uint4(0,0,0,0);
  }

  // P2: per head: QKV | bar | scores+softmax+P | bar | PV+AO | bar | WO (no bar)
  for (int h = 0; h < NH; ++h) {
    // 2a QKV: M=48 x N=192, K=256; A-frags hoisted once, reused for 3 n-tiles/wave
    {
      bf8v aF[3][8];
      #pragma unroll
      for (int m = 0; m < 3; ++m)
        #pragma unroll
        for (int k = 0; k < 8; ++k)
          aF[m][k] = *(const bf8v*)(sN + swz(m*16 + l15, k*32 + l16));
      #pragma unroll
      for (int t3 = 0; t3 < 3; ++t3) {
        const int t = wave*3 + t3;
        const int col = t*16 + l15;
        const int sect = t >> 2;             // 0=Q 1=K 2=V
        const int c = col & 63;
        const int wrow = sect*DM + h*HD + c;
        const float bias = b_qkv[wrow];
        f4v acc[3];
        acc[0] = (f4v){bias,bias,bias,bias}; acc[1] = acc[0]; acc[2] = acc[0];
        #pragma unroll
        for (int k = 0; k < 8; ++k) {
          const bf8v b = wfrag<WBF16>(w_qkv, wbQKV, wrow, k*32 + l16);
          #pragma unroll
          for (int m = 0; m < 3; ++m)
            acc[m] = mfma16(aF[m][k], b, acc[m]);
        }
        if (sect == 2) {
          #pragma unroll
          for (int m = 0; m < 3; ++m)
            #pragma unroll
            for (int j = 0; j < 4; ++j)
              U[U_VT + swzV(c, m*16 + rsub + j)] = f2b(acc[m][j]);
        } else {
          unsigned short* dstb = U + (sect ? U_K : U_Q);
          #pragma unroll
          for (int m = 0; m < 3; ++m)
            #pragma unroll
            for (int j = 0; j < 4; ++j)
              dstb[swzV(m*16 + rsub + j, c)] = f2b(acc[m][j]);
        }
      }
    }
    __syncthreads();

    // 2b scores (waves 0-2) + in-register softmax + P write (own Q rows only)
    if (wave < 3) {
      f4v s3[3];
      s3[0] = (f4v){0.f,0.f,0.f,0.f}; s3[1] = s3[0]; s3[2] = s3[0];
      #pragma unroll
      for (int kk = 0; kk < 2; ++kk) {
        const bf8v a = *(const bf8v*)(U + U_Q + swzV(wave*16 + l15, kk*32 + l16));
        #pragma unroll
        for (int nk = 0; nk < 3; ++nk) {
          const bf8v bb = *(const bf8v*)(U + U_K + swzV(nk*16 + l15, kk*32 + l16));
          s3[nk] = mfma16(a, bb, s3[nk]);
        }
      }
      #pragma unroll
      for (int j = 0; j < 4; ++j) {
        const float v0 = s3[0][j]*0.125f;
        const float v1 = s3[1][j]*0.125f;
        const float v2 = (l15 >= 1) ? -INFINITY : s3[2][j]*0.125f;  // keys 33..47 masked
        float mx = fmaxf(fmaxf(v0, v1), v2);
        mx = fmaxf(mx, __shfl_xor(mx, 1, 64));
        mx = fmaxf(mx, __shfl_xor(mx, 2, 64));
        mx = fmaxf(mx, __shfl_xor(mx, 4, 64));
        mx = fmaxf(mx, __shfl_xor(mx, 8, 64));
        const float e0 = __expf(v0 - mx), e1 = __expf(v1 - mx), e2 = __expf(v2 - mx);
        float den = e0 + e1 + e2;
        den += __shfl_xor(den, 1, 64);
        den += __shfl_xor(den, 2, 64);
        den += __shfl_xor(den, 4, 64);
        den += __shfl_xor(den, 8, 64);
        const float rn = 1.f / den;
        const int row = wave*16 + rsub + j;
        U[U_Q + swzV(row, 0*16 + l15)] = f2b(e0 * rn);
        U[U_Q + swzV(row, 1*16 + l15)] = f2b(e1 * rn);
        U[U_Q + swzV(row, 2*16 + l15)] = f2b(e2 * rn);
      }
    }
    __syncthreads();

    // 2c PV: O = P @ V, wave = d-tile; K=64 (keys 48..63: P garbage x VT zero = 0)
    {
      f4v o4[3];
      o4[0] = (f4v){0.f,0.f,0.f,0.f}; o4[1] = o4[0]; o4[2] = o4[0];
      #pragma unroll
      for (int kk = 0; kk < 2; ++kk) {
        const bf8v bb = *(const bf8v*)(U + U_VT + swzV(wave*16 + l15, kk*32 + l16));
        #pragma unroll
        for (int mq = 0; mq < 3; ++mq) {
          const bf8v a = *(const bf8v*)(U + U_Q + swzV(mq*16 + l15, kk*32 + l16));
          o4[mq] = mfma16(a, bb, o4[mq]);
        }
      }
      #pragma unroll
      for (int mq = 0; mq < 3; ++mq)
        #pragma unroll
        for (int j = 0; j < 4; ++j)
          U[U_AO + swzV(mq*16 + rsub + j, wave*16 + l15)] = f2b(o4[mq][j]);
    }
    __syncthreads();

    // 2d WO: regX += AO_h @ w_o[:, h*64:(h+1)*64]^T  (AO frags hoisted, reused 4x)
    {
      bf8v aA[3][2];
      #pragma unroll
      for (int m = 0; m < 3; ++m)
        #pragma unroll
        for (int kk = 0; kk < 2; ++kk)
          aA[m][kk] = *(const bf8v*)(U + U_AO + swzV(m*16 + l15, kk*32 + l16));
      #pragma unroll
      for (int t4 = 0; t4 < 4; ++t4) {
        const int col = wave*64 + t4*16 + l15;
        #pragma unroll
        for (int k = 0; k < 2; ++k) {
          const bf8v b = wfrag<WBF16>(w_o, wbO, col, h*HD + k*32 + l16);
          #pragma unroll
          for (int m = 0; m < 3; ++m)
            regX[m][t4] = mfma16(aA[m][k], b, regX[m][t4]);
        }
      }
    }
    // no barrier: WO reads AO only; next QKV writes Q/K/VT (disjoint)
  }

  // P3: rmsnorm(X, ln2) from fragments. Row partials -> sRowSum, then xn2 -> sN swz
  #pragma unroll
  for (int m = 0; m < 3; ++m)
    #pragma unroll
    for (int j = 0; j < 4; ++j) {
      float p = 0.f;
      #pragma unroll
      for (int t4 = 0; t4 < 4; ++t4) p += regX[m][t4][j]*regX[m][t4][j];
      p += __shfl_xor(p, 1, 64);
      p += __shfl_xor(p, 2, 64);
      p += __shfl_xor(p, 4, 64);
      p += __shfl_xor(p, 8, 64);
      if (l15 == 0) sRowSum[(m*16 + rsub + j)*4 + wave] = p;
    }
  __syncthreads();
  {
    #pragma unroll
    for (int t4 = 0; t4 < 4; ++t4) {
      const int col = wave*64 + t4*16 + l15;
      const float w2 = ln2_w[col];
      #pragma unroll
      for (int m = 0; m < 3; ++m)
        #pragma unroll
        for (int j = 0; j < 4; ++j) {
          const int row = m*16 + rsub + j;
          const float tot = sRowSum[row*4+0] + sRowSum[row*4+1] + sRowSum[row*4+2] + sRowSum[row*4+3];
          const float rs = rsqrtf(tot*(1.f/DM) + 1e-6f);
          sN[swz(row, col)] = f2b(regX[m][t4][j] * rs * w2);
        }
    }
  }
  __syncthreads();

  // P4: gate/up GEMM -> mid = silu(g)*u -> U swz [48][256]  (A-frags hoisted)
  {
    bf8v aF[3][8];
    #pragma unroll
    for (int m = 0; m < 3; ++m)
      #pragma unroll
      for (int k = 0; k < 8; ++k)
        aF[m][k] = *(const bf8v*)(sN + swz(m*16 + l15, k*32 + l16));
    #pragma unroll
    for (int t4 = 0; t4 < 4; ++t4) {
      const int col = wave*64 + t4*16 + l15;
      f4v aG[3], aU[3];
      #pragma unroll
      for (int m = 0; m < 3; ++m) { aG[m] = (f4v){0.f,0.f,0.f,0.f}; aU[m] = aG[m]; }
      #pragma unroll
      for (int k = 0; k < 8; ++k) {
        const bf8v bg = wfrag<WBF16>(w_gate, wbG, col, k*32 + l16);
        const bf8v bu = wfrag<WBF16>(w_up,   wbU, col, k*32 + l16);
        #pragma unroll
        for (int m = 0; m < 3; ++m) {
          aG[m] = mfma16(aF[m][k], bg, aG[m]);
          aU[m] = mfma16(aF[m][k], bu, aU[m]);
        }
      }
      #pragma unroll
      for (int m = 0; m < 3; ++m)
        #pragma unroll
        for (int j = 0; j < 4; ++j) {
          const float g = aG[m][j];
          const float v = (g / (1.f + __expf(-g))) * aU[m][j];
          U[swz(m*16 + rsub + j, col)] = f2b(v);
        }
    }
  }
  __syncthreads();

  // P5: Z = X + mid @ w_down^T  (C-in = regX; mid frags hoisted) -> sN swz
  {
    bf8v aM[3][8];
    #pragma unroll
    for (int m = 0; m < 3; ++m)
      #pragma unroll
      for (int k = 0; k < 8; ++k)
        aM[m][k] = *(const bf8v*)(U + swz(m*16 + l15, k*32 + l16));
    #pragma unroll
    for (int t4 = 0; t4 < 4; ++t4) {
      const int col = wave*64 + t4*16 + l15;
      f4v acc0 = regX[0][t4];
      f4v acc1 = regX[1][t4];
      f4v acc2 = regX[2][t4];
      #pragma unroll
      for (int k = 0; k < 8; ++k) {
        const bf8v b = wfrag<WBF16>(w_down, wbD, col, k*32 + l16);
        acc0 = mfma16(aM[0][k], b, acc0);
        acc1 = mfma16(aM[1][k], b, acc1);
        acc2 = mfma16(aM[2][k], b, acc2);
      }
      #pragma unroll
      for (int j = 0; j < 4; ++j) {
        sN[swz(0*16 + rsub + j, col)] = f2b(acc0[j]);
        sN[swz(1*16 + rsub + j, col)] = f2b(acc1[j]);
        sN[swz(2*16 + rsub + j, col)] = f2b(acc2[j]);
      }
    }
  }
  __syncthreads();

  // P6: head GEMM on rows 1..32 + MSE vs gathered targets (A-frags hoisted)
  float lsum = 0.f;
  {
    bf8v aH[2][8];
    #pragma unroll
    for (int m = 0; m < 2; ++m)
      #pragma unroll
      for (int k = 0; k < 8; ++k)
        aH[m][k] = *(const bf8v*)(sN + swz(1 + m*16 + l15, k*32 + l16));
    #pragma unroll
    for (int t2 = 0; t2 < 2; ++t2) {
      const int col = (wave*2 + t2)*16 + l15;   // 0..127
      const float bh = b_head[col];
      f4v acc[2];
      acc[0] = (f4v){bh,bh,bh,bh}; acc[1] = acc[0];
      #pragma unroll
      for (int k = 0; k < 8; ++k) {
        const bf8v b = wfrag<WBF16>(w_head, wbH, col, k*32 + l16);
        #pragma unroll
        for (int m = 0; m < 2; ++m)
          acc[m] = mfma16(aH[m][k], b, acc[m]);
      }
      #pragma unroll
      for (int m = 0; m < 2; ++m)
        #pragma unroll
        for (int j = 0; j < 4; ++j) {
          const int row = 1 + m*16 + rsub + j;          // 1..32
          const float tv = target[(size_t)sIdx[row]*DOUT + col];
          const float d = acc[m][j] - tv;
          lsum += d*d;
        }
    }
  }
  lsum = wred(lsum);
  if (lane == 0) sRed[wave] = lsum;
  __syncthreads();
  if (tid == 0)
    partial[bid] = (sRed[0]+sRed[1]+sRed[2]+sRed[3]) * (1.f/(DEG*DOUT));
}

// one-time (per launch) f32 -> bf16 weight conversion into d_ws
__global__ void cvt_w(const float* __restrict__ qkv, const float* __restrict__ o,
                      const float* __restrict__ g, const float* __restrict__ u,
                      const float* __restrict__ dn, const float* __restrict__ hd,
                      unsigned short* __restrict__ out)
{
  const int i = blockIdx.x*NTHREADS + threadIdx.x;
  const int e = i*2;
  if (e >= 491520) return;
  const float* src; int off;
  if      (e < 196608){ src=qkv; off=e; }
  else if (e < 262144){ src=o;  off=e-196608; }
  else if (e < 327680){ src=g;  off=e-262144; }
  else if (e < 393216){ src=u;  off=e-327680; }
  else if (e < 458752){ src=dn; off=e-393216; }
  else                { src=hd; off=e-458752; }
  const float2 v = *(const float2*)(src + off);
  const unsigned int pk = (unsigned int)f2b(v.x) | ((unsigned int)f2b(v.y) << 16);
  *(unsigned int*)(out + e) = pk;
}

__global__ void smtp_reduce(const float* __restrict__ partial, int B, float* __restrict__ out)
{
  __shared__ float sRed[4];
  const int tid = threadIdx.x;
  float s = 0.f;
  for (int i = tid; i < B; i += NTHREADS) s += partial[i];
  s = wred(s);
  if ((tid & 63) == 0) sRed[tid>>6] = s;
  __syncthreads();
  if (tid == 0) out[0] = (sRed[0]+sRed[1]+sRed[2]+sRed[3]) / (float)B;
}

extern "C" void kernel_launch(void* const* d_in, const int* in_sizes, int n_in,
                              void* d_out, int out_size, void* d_ws, size_t ws_size,
                              hipStream_t stream) {
  const float* H        = (const float*)d_in[0];
  const int*   edge     = (const int*)d_in[1];
  const int*   centers  = (const int*)d_in[2];
  const float* target   = (const float*)d_in[3];
  const float* ln_in_w  = (const float*)d_in[5];
  const float* ln1_w    = (const float*)d_in[6];
  const float* ln2_w    = (const float*)d_in[7];
  const float* w_qkv    = (const float*)d_in[8];
  const float* b_qkv    = (const float*)d_in[9];
  const float* w_o      = (const float*)d_in[10];
  const float* b_o      = (const float*)d_in[11];
  const float* w_gate   = (const float*)d_in[12];
  const float* w_up     = (const float*)d_in[13];
  const float* w_down   = (const float*)d_in[14];
  const float* w_head   = (const float*)d_in[15];
  const float* b_head   = (const float*)d_in[16];

  const int B = in_sizes[2];
  const int E = in_sizes[1] / 2;
  const int* dstE = edge + E;

  const size_t WB_ELEMS = 491520;
  const size_t NEED = WB_ELEMS*2 + (size_t)B*4;
  const bool useBf = (ws_size >= NEED);

  if (useBf) {
    unsigned short* wb = (unsigned short*)d_ws;
    float* partial = (float*)((char*)d_ws + WB_ELEMS*2);
    cvt_w<<<960, NTHREADS, 0, stream>>>(w_qkv, w_o, w_gate, w_up, w_down, w_head, wb);
    smtp_center<true><<<B, NTHREADS, 0, stream>>>(H, dstE, centers, target, ln_in_w, ln1_w, ln2_w,
        w_qkv, b_qkv, w_o, b_o, w_gate, w_up, w_down, w_head, b_head, wb, partial);
    smtp_reduce<<<1, NTHREADS, 0, stream>>>(partial, B, (float*)d_out);
  } else {
    float* partial = (float*)d_ws;
    smtp_center<false><<<B, NTHREADS, 0, stream>>>(H, dstE, centers, target, ln_in_w, ln1_w, ln2_w,
        w_qkv, b_qkv, w_o, b_o, w_gate, w_up, w_down, w_head, b_head, (const unsigned short*)d_ws, partial);
    smtp_reduce<<<1, NTHREADS, 0, stream>>>(partial, B, (float*)d_out);
  }
}

// Round 6
// 1632.376 us; speedup vs baseline: 1.5596x; 1.1503x over previous
//
#include <hip/hip_runtime.h>

#define DM 256
#define NH 4
#define HD 64
#define DEG 32
#define LQ 33
#define DOUT 128
#define NTHREADS 256

typedef __attribute__((ext_vector_type(8))) short bf8v;   // 8 bf16 = 4 VGPRs (MFMA A/B frag)
typedef __attribute__((ext_vector_type(4))) float f4v;    // MFMA C/D frag

__device__ __forceinline__ float b2f(unsigned short u){ union{unsigned int i;float f;}v; v.i=((unsigned int)u)<<16; return v.f; }
__device__ __forceinline__ unsigned short f2b(float f){
  union{float f;unsigned int i;}v; v.f=f;
  unsigned int r=v.i+0x7FFFu+((v.i>>16)&1u);
  return (unsigned short)(r>>16);
}
__device__ __forceinline__ float wred(float x){
  #pragma unroll
  for (int o=32;o>=1;o>>=1) x += __shfl_xor(x,o,64);
  return x;
}

// XOR swizzle for [R][256] bf16 LDS tiles read as ds_read_b128 A-fragments
__device__ __forceinline__ int swz(int r, int c){ return r*DM + (((c>>3) ^ (r&7))<<3) + (c&7); }
// XOR swizzle for [R][64] bf16 tiles (Q/P, K, VT, AO)
__device__ __forceinline__ int swzV(int r, int c){ return r*HD + (((c>>3) ^ (r&7))<<3) + (c&7); }

template<bool BF>
__device__ __forceinline__ bf8v wfrag(const float* Wf, const unsigned short* Wb, int row, int e){
  if constexpr (BF) {
    return *(const bf8v*)(Wb + (size_t)row*DM + e);
  } else {
    const float* p = Wf + (size_t)row*DM + e;
    const float4 a = *(const float4*)p;
    const float4 b = *(const float4*)(p+4);
    bf8v r;
    r[0]=(short)(__float_as_uint(a.x)>>16); r[1]=(short)(__float_as_uint(a.y)>>16);
    r[2]=(short)(__float_as_uint(a.z)>>16); r[3]=(short)(__float_as_uint(a.w)>>16);
    r[4]=(short)(__float_as_uint(b.x)>>16); r[5]=(short)(__float_as_uint(b.y)>>16);
    r[6]=(short)(__float_as_uint(b.z)>>16); r[7]=(short)(__float_as_uint(b.w)>>16);
    return r;
  }
}

__device__ __forceinline__ f4v mfma16(bf8v a, bf8v b, f4v c){
  return __builtin_amdgcn_mfma_f32_16x16x32_bf16(a, b, c, 0, 0, 0);
}

// U region (u16 offsets). Q/P overlay; X-staging and Mid use the whole region.
#define U_Q  0       // [48][64] swzV  (P overlays after scores)
#define U_K  3072    // [48][64] swzV
#define U_VT 6144    // [64][64] swzV   VT[d][key]; keys 48..63 stay zero
#define U_AO 10240   // [48][64] swzV
#define U_SZ 13312

template<bool WBF16>
__global__ __launch_bounds__(NTHREADS, 2) void smtp_center(
    const float* __restrict__ H,
    const int* __restrict__ dstE,
    const int* __restrict__ centers,
    const float* __restrict__ target,
    const float* __restrict__ ln_in_w,
    const float* __restrict__ ln1_w,
    const float* __restrict__ ln2_w,
    const float* __restrict__ w_qkv,
    const float* __restrict__ b_qkv,
    const float* __restrict__ w_o,
    const float* __restrict__ b_o,
    const float* __restrict__ w_gate,
    const float* __restrict__ w_up,
    const float* __restrict__ w_down,
    const float* __restrict__ w_head,
    const float* __restrict__ b_head,
    const unsigned short* __restrict__ wb,
    float* __restrict__ partial)
{
  __shared__ __align__(16) unsigned short sN[48*DM];   // xn / xn2 / Z, swizzled
  __shared__ __align__(16) unsigned short U[U_SZ];
  __shared__ float sRowSum[48*4];
  __shared__ int sIdx[48];
  __shared__ float sRed[4];

  const unsigned short* wbQKV = wb;
  const unsigned short* wbO   = wb + 196608;
  const unsigned short* wbG   = wb + 262144;
  const unsigned short* wbU   = wb + 327680;
  const unsigned short* wbD   = wb + 393216;
  const unsigned short* wbH   = wb + 458752;

  const int tid  = threadIdx.x;
  const int lane = tid & 63;
  const int wave = tid >> 6;
  const int bid  = blockIdx.x;
  const int l15  = lane & 15;
  const int l16  = (lane >> 4) * 8;
  const int rsub = (lane >> 4) * 4;

  // P0: star indices
  if (tid < LQ) {
    int ctr = centers[bid];
    sIdx[tid] = (tid == 0) ? ctr : dstE[(size_t)ctr*DEG + (tid-1)];
  }
  __syncthreads();

  // P1: gather + rmsnorm(ln_in) -> X staged in U [48][256] swz; rmsnorm(ln1) -> sN swz
  for (int r = wave; r < LQ; r += 4) {
    const float4 x4 = ((const float4*)(H + (size_t)sIdx[r]*DM))[lane];
    float ss = x4.x*x4.x + x4.y*x4.y + x4.z*x4.z + x4.w*x4.w;
    ss = wred(ss);
    const float rs = rsqrtf(ss*(1.f/DM) + 1e-6f);
    const float4 wi = ((const float4*)ln_in_w)[lane];
    const float xv0 = x4.x*rs*wi.x, xv1 = x4.y*rs*wi.y, xv2 = x4.z*rs*wi.z, xv3 = x4.w*rs*wi.w;
    ushort4 xb; xb.x=f2b(xv0); xb.y=f2b(xv1); xb.z=f2b(xv2); xb.w=f2b(xv3);
    *(ushort4*)(U + swz(r, lane*4)) = xb;
    float s2 = xv0*xv0 + xv1*xv1 + xv2*xv2 + xv3*xv3;
    s2 = wred(s2);
    const float rs2 = rsqrtf(s2*(1.f/DM) + 1e-6f);
    const float4 w1 = ((const float4*)ln1_w)[lane];
    ushort4 yb; yb.x=f2b(xv0*rs2*w1.x); yb.y=f2b(xv1*rs2*w1.y); yb.z=f2b(xv2*rs2*w1.z); yb.w=f2b(xv3*rs2*w1.w);
    *(ushort4*)(sN + swz(r, lane*4)) = yb;
  }
  {
    ushort4 z4; z4.x=0; z4.y=0; z4.z=0; z4.w=0;
    for (int r = LQ + wave; r < 48; r += 4) {
      *(ushort4*)(U  + swz(r, lane*4)) = z4;   // X pad rows (feed regX)
      ((ushort4*)(sN + r*DM))[lane]    = z4;   // zeros are swizzle-invariant
    }
  }
  __syncthreads();

  // P1b: residual X -> per-wave C-fragments regX[m][t4]; fold b_o in once.
  f4v regX[3][4];
  {
    #pragma unroll
    for (int t4 = 0; t4 < 4; ++t4) {
      const int col = wave*64 + t4*16 + l15;
      const float bo = b_o[col];
      #pragma unroll
      for (int m = 0; m < 3; ++m)
        #pragma unroll
        for (int j = 0; j < 4; ++j)
          regX[m][t4][j] = b2f(U[swz(m*16 + rsub + j, col)]) + bo;
    }
  }
  __syncthreads();   // U free for QKV outputs

  // VT pad keys 48..63 = 0 (once; disjoint from QKV's key 0..47 writes)
  if (tid < 128) {
    const int d = tid >> 1;
    const int key = 48 + (tid & 1)*8;
    *(uint4*)&U[U_VT + swzV(d, key)] = make_uint4(0,0,0,0);
  }

  // P2: per head: QKV | bar | scores+softmax+P | bar | PV+AO | bar | WO (no bar)
  for (int h = 0; h < NH; ++h) {
    // 2a QKV: M=48 x N=192, K=256; k-outer, aF[3] live per k (12 VGPR), acc[3][3] in AGPR
    {
      int wrow[3]; int sect[3]; float bias[3];
      #pragma unroll
      for (int t3 = 0; t3 < 3; ++t3) {
        const int t = wave*3 + t3;
        const int col = t*16 + l15;
        sect[t3] = t >> 2;                 // 0=Q 1=K 2=V
        wrow[t3] = sect[t3]*DM + h*HD + (col & 63);
        bias[t3] = b_qkv[wrow[t3]];
      }
      f4v acc[3][3];
      #pragma unroll
      for (int t3 = 0; t3 < 3; ++t3)
        #pragma unroll
        for (int m = 0; m < 3; ++m)
          acc[t3][m] = (f4v){bias[t3],bias[t3],bias[t3],bias[t3]};
      #pragma unroll
      for (int k = 0; k < 8; ++k) {
        bf8v aF[3];
        #pragma unroll
        for (int m = 0; m < 3; ++m)
          aF[m] = *(const bf8v*)(sN + swz(m*16 + l15, k*32 + l16));
        #pragma unroll
        for (int t3 = 0; t3 < 3; ++t3) {
          const bf8v b = wfrag<WBF16>(w_qkv, wbQKV, wrow[t3], k*32 + l16);
          #pragma unroll
          for (int m = 0; m < 3; ++m)
            acc[t3][m] = mfma16(aF[m], b, acc[t3][m]);
        }
      }
      #pragma unroll
      for (int t3 = 0; t3 < 3; ++t3) {
        const int c = wrow[t3] & 63;
        if (sect[t3] == 2) {               // V -> VT[d][key]
          #pragma unroll
          for (int m = 0; m < 3; ++m)
            #pragma unroll
            for (int j = 0; j < 4; ++j)
              U[U_VT + swzV(c, m*16 + rsub + j)] = f2b(acc[t3][m][j]);
        } else {
          unsigned short* dstb = U + (sect[t3] ? U_K : U_Q);
          #pragma unroll
          for (int m = 0; m < 3; ++m)
            #pragma unroll
            for (int j = 0; j < 4; ++j)
              dstb[swzV(m*16 + rsub + j, c)] = f2b(acc[t3][m][j]);
        }
      }
    }
    __syncthreads();

    // 2b scores (waves 0-2) + in-register softmax + P write (own Q rows only)
    if (wave < 3) {
      f4v s3[3];
      s3[0] = (f4v){0.f,0.f,0.f,0.f}; s3[1] = s3[0]; s3[2] = s3[0];
      #pragma unroll
      for (int kk = 0; kk < 2; ++kk) {
        const bf8v a = *(const bf8v*)(U + U_Q + swzV(wave*16 + l15, kk*32 + l16));
        #pragma unroll
        for (int nk = 0; nk < 3; ++nk) {
          const bf8v bb = *(const bf8v*)(U + U_K + swzV(nk*16 + l15, kk*32 + l16));
          s3[nk] = mfma16(a, bb, s3[nk]);
        }
      }
      #pragma unroll
      for (int j = 0; j < 4; ++j) {
        const float v0 = s3[0][j]*0.125f;
        const float v1 = s3[1][j]*0.125f;
        const float v2 = (l15 >= 1) ? -INFINITY : s3[2][j]*0.125f;  // keys 33..47 masked
        float mx = fmaxf(fmaxf(v0, v1), v2);
        mx = fmaxf(mx, __shfl_xor(mx, 1, 64));
        mx = fmaxf(mx, __shfl_xor(mx, 2, 64));
        mx = fmaxf(mx, __shfl_xor(mx, 4, 64));
        mx = fmaxf(mx, __shfl_xor(mx, 8, 64));
        const float e0 = __expf(v0 - mx), e1 = __expf(v1 - mx), e2 = __expf(v2 - mx);
        float den = e0 + e1 + e2;
        den += __shfl_xor(den, 1, 64);
        den += __shfl_xor(den, 2, 64);
        den += __shfl_xor(den, 4, 64);
        den += __shfl_xor(den, 8, 64);
        const float rn = 1.f / den;
        const int row = wave*16 + rsub + j;
        U[U_Q + swzV(row, 0*16 + l15)] = f2b(e0 * rn);
        U[U_Q + swzV(row, 1*16 + l15)] = f2b(e1 * rn);
        U[U_Q + swzV(row, 2*16 + l15)] = f2b(e2 * rn);
      }
    }
    __syncthreads();

    // 2c PV: O = P @ V, wave = d-tile; K=64 (keys 48..63: P garbage x VT zero = 0)
    {
      f4v o4[3];
      o4[0] = (f4v){0.f,0.f,0.f,0.f}; o4[1] = o4[0]; o4[2] = o4[0];
      #pragma unroll
      for (int kk = 0; kk < 2; ++kk) {
        const bf8v bb = *(const bf8v*)(U + U_VT + swzV(wave*16 + l15, kk*32 + l16));
        #pragma unroll
        for (int mq = 0; mq < 3; ++mq) {
          const bf8v a = *(const bf8v*)(U + U_Q + swzV(mq*16 + l15, kk*32 + l16));
          o4[mq] = mfma16(a, bb, o4[mq]);
        }
      }
      #pragma unroll
      for (int mq = 0; mq < 3; ++mq)
        #pragma unroll
        for (int j = 0; j < 4; ++j)
          U[U_AO + swzV(mq*16 + rsub + j, wave*16 + l15)] = f2b(o4[mq][j]);
    }
    __syncthreads();

    // 2d WO: regX += AO_h @ w_o^T slice; k-outer, aA[3] per k
    #pragma unroll
    for (int k = 0; k < 2; ++k) {
      bf8v aA[3];
      #pragma unroll
      for (int m = 0; m < 3; ++m)
        aA[m] = *(const bf8v*)(U + U_AO + swzV(m*16 + l15, k*32 + l16));
      #pragma unroll
      for (int t4 = 0; t4 < 4; ++t4) {
        const int col = wave*64 + t4*16 + l15;
        const bf8v b = wfrag<WBF16>(w_o, wbO, col, h*HD + k*32 + l16);
        #pragma unroll
        for (int m = 0; m < 3; ++m)
          regX[m][t4] = mfma16(aA[m], b, regX[m][t4]);
      }
    }
    // no barrier: WO reads AO only; next QKV writes Q/K/VT (disjoint)
  }

  // P3: rmsnorm(X, ln2) from fragments. Row partials -> sRowSum, then xn2 -> sN swz
  #pragma unroll
  for (int m = 0; m < 3; ++m)
    #pragma unroll
    for (int j = 0; j < 4; ++j) {
      float p = 0.f;
      #pragma unroll
      for (int t4 = 0; t4 < 4; ++t4) p += regX[m][t4][j]*regX[m][t4][j];
      p += __shfl_xor(p, 1, 64);
      p += __shfl_xor(p, 2, 64);
      p += __shfl_xor(p, 4, 64);
      p += __shfl_xor(p, 8, 64);
      if (l15 == 0) sRowSum[(m*16 + rsub + j)*4 + wave] = p;
    }
  __syncthreads();
  {
    #pragma unroll
    for (int t4 = 0; t4 < 4; ++t4) {
      const int col = wave*64 + t4*16 + l15;
      const float w2 = ln2_w[col];
      #pragma unroll
      for (int m = 0; m < 3; ++m)
        #pragma unroll
        for (int j = 0; j < 4; ++j) {
          const int row = m*16 + rsub + j;
          const float tot = sRowSum[row*4+0] + sRowSum[row*4+1] + sRowSum[row*4+2] + sRowSum[row*4+3];
          const float rs = rsqrtf(tot*(1.f/DM) + 1e-6f);
          sN[swz(row, col)] = f2b(regX[m][t4][j] * rs * w2);
        }
    }
  }
  __syncthreads();

  // P4: gate/up GEMM -> mid = silu(g)*u -> U swz [48][256]; k-outer, 2 passes (acc bound)
  #pragma unroll
  for (int p = 0; p < 2; ++p) {
    f4v aG[2][3], aU[2][3];
    #pragma unroll
    for (int tt = 0; tt < 2; ++tt)
      #pragma unroll
      for (int m = 0; m < 3; ++m) { aG[tt][m] = (f4v){0.f,0.f,0.f,0.f}; aU[tt][m] = aG[tt][m]; }
    #pragma unroll
    for (int k = 0; k < 8; ++k) {
      bf8v aF[3];
      #pragma unroll
      for (int m = 0; m < 3; ++m)
        aF[m] = *(const bf8v*)(sN + swz(m*16 + l15, k*32 + l16));
      #pragma unroll
      for (int tt = 0; tt < 2; ++tt) {
        const int col = wave*64 + (p*2 + tt)*16 + l15;
        const bf8v bg = wfrag<WBF16>(w_gate, wbG, col, k*32 + l16);
        const bf8v bu = wfrag<WBF16>(w_up,   wbU, col, k*32 + l16);
        #pragma unroll
        for (int m = 0; m < 3; ++m) {
          aG[tt][m] = mfma16(aF[m], bg, aG[tt][m]);
          aU[tt][m] = mfma16(aF[m], bu, aU[tt][m]);
        }
      }
    }
    #pragma unroll
    for (int tt = 0; tt < 2; ++tt) {
      const int col = wave*64 + (p*2 + tt)*16 + l15;
      #pragma unroll
      for (int m = 0; m < 3; ++m)
        #pragma unroll
        for (int j = 0; j < 4; ++j) {
          const float g = aG[tt][m][j];
          const float v = (g / (1.f + __expf(-g))) * aU[tt][m][j];
          U[swz(m*16 + rsub + j, col)] = f2b(v);
        }
    }
  }
  __syncthreads();

  // P5: Z = X + mid @ w_down^T  (C-in/out = regX); k-outer, aM[3] per k
  #pragma unroll
  for (int k = 0; k < 8; ++k) {
    bf8v aM[3];
    #pragma unroll
    for (int m = 0; m < 3; ++m)
      aM[m] = *(const bf8v*)(U + swz(m*16 + l15, k*32 + l16));
    #pragma unroll
    for (int t4 = 0; t4 < 4; ++t4) {
      const int col = wave*64 + t4*16 + l15;
      const bf8v b = wfrag<WBF16>(w_down, wbD, col, k*32 + l16);
      #pragma unroll
      for (int m = 0; m < 3; ++m)
        regX[m][t4] = mfma16(aM[m], b, regX[m][t4]);
    }
  }
  __syncthreads();   // all reads of U(mid) done

  // P5b: Z -> sN swz
  #pragma unroll
  for (int t4 = 0; t4 < 4; ++t4) {
    const int col = wave*64 + t4*16 + l15;
    #pragma unroll
    for (int m = 0; m < 3; ++m)
      #pragma unroll
      for (int j = 0; j < 4; ++j)
        sN[swz(m*16 + rsub + j, col)] = f2b(regX[m][t4][j]);
  }
  __syncthreads();

  // P6: head GEMM on rows 1..32 + MSE vs gathered targets; k-outer
  float lsum = 0.f;
  {
    int cols[2]; f4v acc[2][2];
    #pragma unroll
    for (int t2 = 0; t2 < 2; ++t2) {
      cols[t2] = (wave*2 + t2)*16 + l15;   // 0..127
      const float bh = b_head[cols[t2]];
      acc[t2][0] = (f4v){bh,bh,bh,bh}; acc[t2][1] = acc[t2][0];
    }
    #pragma unroll
    for (int k = 0; k < 8; ++k) {
      bf8v aH[2];
      #pragma unroll
      for (int m = 0; m < 2; ++m)
        aH[m] = *(const bf8v*)(sN + swz(1 + m*16 + l15, k*32 + l16));
      #pragma unroll
      for (int t2 = 0; t2 < 2; ++t2) {
        const bf8v b = wfrag<WBF16>(w_head, wbH, cols[t2], k*32 + l16);
        #pragma unroll
        for (int m = 0; m < 2; ++m)
          acc[t2][m] = mfma16(aH[m], b, acc[t2][m]);
      }
    }
    #pragma unroll
    for (int t2 = 0; t2 < 2; ++t2)
      #pragma unroll
      for (int m = 0; m < 2; ++m)
        #pragma unroll
        for (int j = 0; j < 4; ++j) {
          const int row = 1 + m*16 + rsub + j;          // 1..32
          const float tv = target[(size_t)sIdx[row]*DOUT + cols[t2]];
          const float d = acc[t2][m][j] - tv;
          lsum += d*d;
        }
  }
  lsum = wred(lsum);
  if (lane == 0) sRed[wave] = lsum;
  __syncthreads();
  if (tid == 0)
    partial[bid] = (sRed[0]+sRed[1]+sRed[2]+sRed[3]) * (1.f/(DEG*DOUT));
}

// one-time (per launch) f32 -> bf16 weight conversion into d_ws
__global__ void cvt_w(const float* __restrict__ qkv, const float* __restrict__ o,
                      const float* __restrict__ g, const float* __restrict__ u,
                      const float* __restrict__ dn, const float* __restrict__ hd,
                      unsigned short* __restrict__ out)
{
  const int i = blockIdx.x*NTHREADS + threadIdx.x;
  const int e = i*2;
  if (e >= 491520) return;
  const float* src; int off;
  if      (e < 196608){ src=qkv; off=e; }
  else if (e < 262144){ src=o;  off=e-196608; }
  else if (e < 327680){ src=g;  off=e-262144; }
  else if (e < 393216){ src=u;  off=e-327680; }
  else if (e < 458752){ src=dn; off=e-393216; }
  else                { src=hd; off=e-458752; }
  const float2 v = *(const float2*)(src + off);
  const unsigned int pk = (unsigned int)f2b(v.x) | ((unsigned int)f2b(v.y) << 16);
  *(unsigned int*)(out + e) = pk;
}

__global__ void smtp_reduce(const float* __restrict__ partial, int B, float* __restrict__ out)
{
  __shared__ float sRed[4];
  const int tid = threadIdx.x;
  float s = 0.f;
  for (int i = tid; i < B; i += NTHREADS) s += partial[i];
  s = wred(s);
  if ((tid & 63) == 0) sRed[tid>>6] = s;
  __syncthreads();
  if (tid == 0) out[0] = (sRed[0]+sRed[1]+sRed[2]+sRed[3]) / (float)B;
}

extern "C" void kernel_launch(void* const* d_in, const int* in_sizes, int n_in,
                              void* d_out, int out_size, void* d_ws, size_t ws_size,
                              hipStream_t stream) {
  const float* H        = (const float*)d_in[0];
  const int*   edge     = (const int*)d_in[1];
  const int*   centers  = (const int*)d_in[2];
  const float* target   = (const float*)d_in[3];
  const float* ln_in_w  = (const float*)d_in[5];
  const float* ln1_w    = (const float*)d_in[6];
  const float* ln2_w    = (const float*)d_in[7];
  const float* w_qkv    = (const float*)d_in[8];
  const float* b_qkv    = (const float*)d_in[9];
  const float* w_o      = (const float*)d_in[10];
  const float* b_o      = (const float*)d_in[11];
  const float* w_gate   = (const float*)d_in[12];
  const float* w_up     = (const float*)d_in[13];
  const float* w_down   = (const float*)d_in[14];
  const float* w_head   = (const float*)d_in[15];
  const float* b_head   = (const float*)d_in[16];

  const int B = in_sizes[2];
  const int E = in_sizes[1] / 2;
  const int* dstE = edge + E;

  const size_t WB_ELEMS = 491520;
  const size_t NEED = WB_ELEMS*2 + (size_t)B*4;
  const bool useBf = (ws_size >= NEED);

  if (useBf) {
    unsigned short* wb = (unsigned short*)d_ws;
    float* partial = (float*)((char*)d_ws + WB_ELEMS*2);
    cvt_w<<<960, NTHREADS, 0, stream>>>(w_qkv, w_o, w_gate, w_up, w_down, w_head, wb);
    smtp_center<true><<<B, NTHREADS, 0, stream>>>(H, dstE, centers, target, ln_in_w, ln1_w, ln2_w,
        w_qkv, b_qkv, w_o, b_o, w_gate, w_up, w_down, w_head, b_head, wb, partial);
    smtp_reduce<<<1, NTHREADS, 0, stream>>>(partial, B, (float*)d_out);
  } else {
    float* partial = (float*)d_ws;
    smtp_center<false><<<B, NTHREADS, 0, stream>>>(H, dstE, centers, target, ln_in_w, ln1_w, ln2_w,
        w_qkv, b_qkv, w_o, b_o, w_gate, w_up, w_down, w_head, b_head, (const unsigned short*)d_ws, partial);
    smtp_reduce<<<1, NTHREADS, 0, stream>>>(partial, B, (float*)d_out);
  }
}

// Round 7
// 1159.269 us; speedup vs baseline: 2.1960x; 1.4081x over previous
//
#include <hip/hip_runtime.h>

#define DM 256
#define NH 4
#define HD 64
#define DEG 32
#define LQ 33
#define DOUT 128
#define NTHREADS 256
#define XTP 52   // XT row-pad: col*52+row keeps b64 frags 8B-aligned, ~2-way banks

typedef __attribute__((ext_vector_type(8))) short bf8v;   // 8 bf16 = 4 VGPRs (MFMA A/B frag)
typedef __attribute__((ext_vector_type(4))) float f4v;    // MFMA C/D frag

__device__ __forceinline__ float b2f(unsigned short u){ union{unsigned int i;float f;}v; v.i=((unsigned int)u)<<16; return v.f; }
__device__ __forceinline__ unsigned short f2b(float f){
  union{float f;unsigned int i;}v; v.f=f;
  unsigned int r=v.i+0x7FFFu+((v.i>>16)&1u);
  return (unsigned short)(r>>16);
}
__device__ __forceinline__ float wred(float x){
  #pragma unroll
  for (int o=32;o>=1;o>>=1) x += __shfl_xor(x,o,64);
  return x;
}

// XOR swizzle for [R][256] bf16 LDS tiles read as ds_read_b128 A-fragments
__device__ __forceinline__ int swz(int r, int c){ return r*DM + (((c>>3) ^ (r&7))<<3) + (c&7); }
// XOR swizzle for [R][64] bf16 tiles (Q/P, K, VT, AO)
__device__ __forceinline__ int swzV(int r, int c){ return r*HD + (((c>>3) ^ (r&7))<<3) + (c&7); }

template<bool BF>
__device__ __forceinline__ bf8v wfrag(const float* Wf, const unsigned short* Wb, int row, int e){
  if constexpr (BF) {
    return *(const bf8v*)(Wb + (size_t)row*DM + e);
  } else {
    const float* p = Wf + (size_t)row*DM + e;
    const float4 a = *(const float4*)p;
    const float4 b = *(const float4*)(p+4);
    bf8v r;
    r[0]=(short)(__float_as_uint(a.x)>>16); r[1]=(short)(__float_as_uint(a.y)>>16);
    r[2]=(short)(__float_as_uint(a.z)>>16); r[3]=(short)(__float_as_uint(a.w)>>16);
    r[4]=(short)(__float_as_uint(b.x)>>16); r[5]=(short)(__float_as_uint(b.y)>>16);
    r[6]=(short)(__float_as_uint(b.z)>>16); r[7]=(short)(__float_as_uint(b.w)>>16);
    return r;
  }
}

__device__ __forceinline__ f4v mfma16(bf8v a, bf8v b, f4v c){
  return __builtin_amdgcn_mfma_f32_16x16x32_bf16(a, b, c, 0, 0, 0);
}

// U region (u16 offsets). Q/P overlay; Mid reuses whole region after attention.
#define U_Q  0       // [48][64] swzV  (P overlays after scores)
#define U_K  3072    // [48][64] swzV
#define U_VT 6144    // [64][64] swzV   VT[d][key]; keys 48..63 stay zero
#define U_AO 10240   // [48][64] swzV
#define U_SZ 13312

template<bool WBF16>
__global__ __launch_bounds__(NTHREADS, 2) void smtp_center(
    const float* __restrict__ H,
    const int* __restrict__ dstE,
    const int* __restrict__ centers,
    const float* __restrict__ target,
    const float* __restrict__ ln_in_w,
    const float* __restrict__ ln1_w,
    const float* __restrict__ ln2_w,
    const float* __restrict__ w_qkv,
    const float* __restrict__ b_qkv,
    const float* __restrict__ w_o,
    const float* __restrict__ b_o,
    const float* __restrict__ w_gate,
    const float* __restrict__ w_up,
    const float* __restrict__ w_down,
    const float* __restrict__ w_head,
    const float* __restrict__ b_head,
    const unsigned short* __restrict__ wb,
    float* __restrict__ partial)
{
  __shared__ __align__(16) unsigned short sN[48*DM];    // xn / xn2 / Z, swizzled
  __shared__ __align__(16) unsigned short sXT[256*XTP]; // residual X, transposed [col][row]
  __shared__ __align__(16) unsigned short U[U_SZ];
  __shared__ float sRowSum[48*4];
  __shared__ int sIdx[48];
  __shared__ float sRed[4];

  const unsigned short* wbQKV = wb;
  const unsigned short* wbO   = wb + 196608;
  const unsigned short* wbG   = wb + 262144;
  const unsigned short* wbU   = wb + 327680;
  const unsigned short* wbD   = wb + 393216;
  const unsigned short* wbH   = wb + 458752;

  const int tid  = threadIdx.x;
  const int lane = tid & 63;
  const int wave = tid >> 6;
  const int bid  = blockIdx.x;
  const int l15  = lane & 15;
  const int l16  = (lane >> 4) * 8;
  const int rsub = (lane >> 4) * 4;

  // P0: star indices
  if (tid < LQ) {
    int ctr = centers[bid];
    sIdx[tid] = (tid == 0) ? ctr : dstE[(size_t)ctr*DEG + (tid-1)];
  }
  __syncthreads();

  // P1: gather + rmsnorm(ln_in) -> XT (transposed); rmsnorm(ln1) -> sN swz
  for (int r = wave; r < LQ; r += 4) {
    const float4 x4 = ((const float4*)(H + (size_t)sIdx[r]*DM))[lane];
    float ss = x4.x*x4.x + x4.y*x4.y + x4.z*x4.z + x4.w*x4.w;
    ss = wred(ss);
    const float rs = rsqrtf(ss*(1.f/DM) + 1e-6f);
    const float4 wi = ((const float4*)ln_in_w)[lane];
    const float xv0 = x4.x*rs*wi.x, xv1 = x4.y*rs*wi.y, xv2 = x4.z*rs*wi.z, xv3 = x4.w*rs*wi.w;
    sXT[(lane*4+0)*XTP + r] = f2b(xv0);
    sXT[(lane*4+1)*XTP + r] = f2b(xv1);
    sXT[(lane*4+2)*XTP + r] = f2b(xv2);
    sXT[(lane*4+3)*XTP + r] = f2b(xv3);
    float s2 = xv0*xv0 + xv1*xv1 + xv2*xv2 + xv3*xv3;
    s2 = wred(s2);
    const float rs2 = rsqrtf(s2*(1.f/DM) + 1e-6f);
    const float4 w1 = ((const float4*)ln1_w)[lane];
    ushort4 yb; yb.x=f2b(xv0*rs2*w1.x); yb.y=f2b(xv1*rs2*w1.y); yb.z=f2b(xv2*rs2*w1.z); yb.w=f2b(xv3*rs2*w1.w);
    *(ushort4*)(sN + swz(r, lane*4)) = yb;
  }
  {
    ushort4 z4; z4.x=0; z4.y=0; z4.z=0; z4.w=0;
    for (int r = LQ + wave; r < 48; r += 4) {
      sXT[(lane*4+0)*XTP + r] = 0;
      sXT[(lane*4+1)*XTP + r] = 0;
      sXT[(lane*4+2)*XTP + r] = 0;
      sXT[(lane*4+3)*XTP + r] = 0;
      ((ushort4*)(sN + r*DM))[lane] = z4;   // zeros are swizzle-invariant
    }
  }
  // VT pad keys 48..63 = 0 (disjoint from QKV's key 0..47 writes; complete before first PV)
  if (tid < 128) {
    const int d = tid >> 1;
    const int key = 48 + (tid & 1)*8;
    *(uint4*)&U[U_VT + swzV(d, key)] = make_uint4(0,0,0,0);
  }
  __syncthreads();

  // P2: per head: QKV | bar | scores+softmax+P | bar | PV+AO | bar | WO (no bar)
  for (int h = 0; h < NH; ++h) {
    // 2a QKV: M=48 x N=192, K=256; k-outer, aF[3] per k, acc[3][3]
    {
      int wrow[3]; int sect[3];
      #pragma unroll
      for (int t3 = 0; t3 < 3; ++t3) {
        const int t = wave*3 + t3;
        const int col = t*16 + l15;
        sect[t3] = t >> 2;                 // 0=Q 1=K 2=V
        wrow[t3] = sect[t3]*DM + h*HD + (col & 63);
      }
      f4v acc[3][3];
      #pragma unroll
      for (int t3 = 0; t3 < 3; ++t3) {
        const float bias = b_qkv[wrow[t3]];
        #pragma unroll
        for (int m = 0; m < 3; ++m)
          acc[t3][m] = (f4v){bias,bias,bias,bias};
      }
      #pragma unroll
      for (int k = 0; k < 8; ++k) {
        bf8v aF[3];
        #pragma unroll
        for (int m = 0; m < 3; ++m)
          aF[m] = *(const bf8v*)(sN + swz(m*16 + l15, k*32 + l16));
        #pragma unroll
        for (int t3 = 0; t3 < 3; ++t3) {
          const bf8v b = wfrag<WBF16>(w_qkv, wbQKV, wrow[t3], k*32 + l16);
          #pragma unroll
          for (int m = 0; m < 3; ++m)
            acc[t3][m] = mfma16(aF[m], b, acc[t3][m]);
        }
      }
      #pragma unroll
      for (int t3 = 0; t3 < 3; ++t3) {
        const int c = wrow[t3] & 63;
        if (sect[t3] == 2) {               // V -> VT[d][key]
          #pragma unroll
          for (int m = 0; m < 3; ++m)
            #pragma unroll
            for (int j = 0; j < 4; ++j)
              U[U_VT + swzV(c, m*16 + rsub + j)] = f2b(acc[t3][m][j]);
        } else {
          unsigned short* dstb = U + (sect[t3] ? U_K : U_Q);
          #pragma unroll
          for (int m = 0; m < 3; ++m)
            #pragma unroll
            for (int j = 0; j < 4; ++j)
              dstb[swzV(m*16 + rsub + j, c)] = f2b(acc[t3][m][j]);
        }
      }
    }
    __syncthreads();

    // 2b scores (waves 0-2) + in-register softmax + P write (own Q rows only)
    if (wave < 3) {
      f4v s3[3];
      s3[0] = (f4v){0.f,0.f,0.f,0.f}; s3[1] = s3[0]; s3[2] = s3[0];
      #pragma unroll
      for (int kk = 0; kk < 2; ++kk) {
        const bf8v a = *(const bf8v*)(U + U_Q + swzV(wave*16 + l15, kk*32 + l16));
        #pragma unroll
        for (int nk = 0; nk < 3; ++nk) {
          const bf8v bb = *(const bf8v*)(U + U_K + swzV(nk*16 + l15, kk*32 + l16));
          s3[nk] = mfma16(a, bb, s3[nk]);
        }
      }
      #pragma unroll
      for (int j = 0; j < 4; ++j) {
        const float v0 = s3[0][j]*0.125f;
        const float v1 = s3[1][j]*0.125f;
        const float v2 = (l15 >= 1) ? -INFINITY : s3[2][j]*0.125f;  // keys 33..47 masked
        float mx = fmaxf(fmaxf(v0, v1), v2);
        mx = fmaxf(mx, __shfl_xor(mx, 1, 64));
        mx = fmaxf(mx, __shfl_xor(mx, 2, 64));
        mx = fmaxf(mx, __shfl_xor(mx, 4, 64));
        mx = fmaxf(mx, __shfl_xor(mx, 8, 64));
        const float e0 = __expf(v0 - mx), e1 = __expf(v1 - mx), e2 = __expf(v2 - mx);
        float den = e0 + e1 + e2;
        den += __shfl_xor(den, 1, 64);
        den += __shfl_xor(den, 2, 64);
        den += __shfl_xor(den, 4, 64);
        den += __shfl_xor(den, 8, 64);
        const float rn = 1.f / den;
        const int row = wave*16 + rsub + j;
        U[U_Q + swzV(row, 0*16 + l15)] = f2b(e0 * rn);
        U[U_Q + swzV(row, 1*16 + l15)] = f2b(e1 * rn);
        U[U_Q + swzV(row, 2*16 + l15)] = f2b(e2 * rn);
      }
    }
    __syncthreads();

    // 2c PV: O = P @ V, wave = d-tile; K=64 (keys 48..63: P garbage x VT zero = 0)
    {
      f4v o4[3];
      o4[0] = (f4v){0.f,0.f,0.f,0.f}; o4[1] = o4[0]; o4[2] = o4[0];
      #pragma unroll
      for (int kk = 0; kk < 2; ++kk) {
        const bf8v bb = *(const bf8v*)(U + U_VT + swzV(wave*16 + l15, kk*32 + l16));
        #pragma unroll
        for (int mq = 0; mq < 3; ++mq) {
          const bf8v a = *(const bf8v*)(U + U_Q + swzV(mq*16 + l15, kk*32 + l16));
          o4[mq] = mfma16(a, bb, o4[mq]);
        }
      }
      #pragma unroll
      for (int mq = 0; mq < 3; ++mq)
        #pragma unroll
        for (int j = 0; j < 4; ++j)
          U[U_AO + swzV(mq*16 + rsub + j, wave*16 + l15)] = f2b(o4[mq][j]);
    }
    __syncthreads();

    // 2d WO: X(own cols) += AO_h @ w_o^T slice; X lives in XT (wave-private cols, no bar)
    {
      f4v acc[3][4];
      #pragma unroll
      for (int t4 = 0; t4 < 4; ++t4) {
        const int col = wave*64 + t4*16 + l15;
        const float bo = (h==0) ? b_o[col] : 0.f;
        #pragma unroll
        for (int m = 0; m < 3; ++m) {
          const ushort4 xv = *(const ushort4*)&sXT[col*XTP + m*16 + rsub];
          acc[m][t4] = (f4v){b2f(xv.x)+bo, b2f(xv.y)+bo, b2f(xv.z)+bo, b2f(xv.w)+bo};
        }
      }
      #pragma unroll
      for (int k = 0; k < 2; ++k) {
        bf8v aA[3];
        #pragma unroll
        for (int m = 0; m < 3; ++m)
          aA[m] = *(const bf8v*)(U + U_AO + swzV(m*16 + l15, k*32 + l16));
        #pragma unroll
        for (int t4 = 0; t4 < 4; ++t4) {
          const int col = wave*64 + t4*16 + l15;
          const bf8v b = wfrag<WBF16>(w_o, wbO, col, h*HD + k*32 + l16);
          #pragma unroll
          for (int m = 0; m < 3; ++m)
            acc[m][t4] = mfma16(aA[m], b, acc[m][t4]);
        }
      }
      #pragma unroll
      for (int t4 = 0; t4 < 4; ++t4) {
        const int col = wave*64 + t4*16 + l15;
        #pragma unroll
        for (int m = 0; m < 3; ++m) {
          ushort4 xv;
          xv.x = f2b(acc[m][t4][0]); xv.y = f2b(acc[m][t4][1]);
          xv.z = f2b(acc[m][t4][2]); xv.w = f2b(acc[m][t4][3]);
          *(ushort4*)&sXT[col*XTP + m*16 + rsub] = xv;
        }
      }
    }
    // no barrier: WO touches XT(own cols)+AO only; next QKV writes Q/K/VT (disjoint)
  }

  // P3: rmsnorm(X, ln2): per-row partial squares from XT -> sRowSum, then xn2 -> sN swz
  #pragma unroll
  for (int m = 0; m < 3; ++m) {
    float p0=0.f, p1=0.f, p2=0.f, p3=0.f;
    #pragma unroll
    for (int t4 = 0; t4 < 4; ++t4) {
      const int col = wave*64 + t4*16 + l15;
      const ushort4 xv = *(const ushort4*)&sXT[col*XTP + m*16 + rsub];
      const float x0=b2f(xv.x), x1=b2f(xv.y), x2=b2f(xv.z), x3=b2f(xv.w);
      p0 += x0*x0; p1 += x1*x1; p2 += x2*x2; p3 += x3*x3;
    }
    float q[4] = {p0,p1,p2,p3};
    #pragma unroll
    for (int j = 0; j < 4; ++j) {
      float v = q[j];
      v += __shfl_xor(v, 1, 64);
      v += __shfl_xor(v, 2, 64);
      v += __shfl_xor(v, 4, 64);
      v += __shfl_xor(v, 8, 64);
      if (l15 == 0) sRowSum[(m*16 + rsub + j)*4 + wave] = v;
    }
  }
  __syncthreads();
  {
    #pragma unroll
    for (int t4 = 0; t4 < 4; ++t4) {
      const int col = wave*64 + t4*16 + l15;
      const float w2 = ln2_w[col];
      #pragma unroll
      for (int m = 0; m < 3; ++m) {
        const ushort4 xv = *(const ushort4*)&sXT[col*XTP + m*16 + rsub];
        const float xf[4] = {b2f(xv.x), b2f(xv.y), b2f(xv.z), b2f(xv.w)};
        #pragma unroll
        for (int j = 0; j < 4; ++j) {
          const int row = m*16 + rsub + j;
          const float tot = sRowSum[row*4+0] + sRowSum[row*4+1] + sRowSum[row*4+2] + sRowSum[row*4+3];
          const float rs = rsqrtf(tot*(1.f/DM) + 1e-6f);
          sN[swz(row, col)] = f2b(xf[j] * rs * w2);
        }
      }
    }
  }
  __syncthreads();

  // P4: gate/up GEMM -> mid = silu(g)*u -> U swz [48][256]; k-outer, 2 passes
  #pragma unroll
  for (int p = 0; p < 2; ++p) {
    f4v aG[2][3], aU[2][3];
    #pragma unroll
    for (int tt = 0; tt < 2; ++tt)
      #pragma unroll
      for (int m = 0; m < 3; ++m) { aG[tt][m] = (f4v){0.f,0.f,0.f,0.f}; aU[tt][m] = aG[tt][m]; }
    #pragma unroll
    for (int k = 0; k < 8; ++k) {
      bf8v aF[3];
      #pragma unroll
      for (int m = 0; m < 3; ++m)
        aF[m] = *(const bf8v*)(sN + swz(m*16 + l15, k*32 + l16));
      #pragma unroll
      for (int tt = 0; tt < 2; ++tt) {
        const int col = wave*64 + (p*2 + tt)*16 + l15;
        const bf8v bg = wfrag<WBF16>(w_gate, wbG, col, k*32 + l16);
        const bf8v bu = wfrag<WBF16>(w_up,   wbU, col, k*32 + l16);
        #pragma unroll
        for (int m = 0; m < 3; ++m) {
          aG[tt][m] = mfma16(aF[m], bg, aG[tt][m]);
          aU[tt][m] = mfma16(aF[m], bu, aU[tt][m]);
        }
      }
    }
    #pragma unroll
    for (int tt = 0; tt < 2; ++tt) {
      const int col = wave*64 + (p*2 + tt)*16 + l15;
      #pragma unroll
      for (int m = 0; m < 3; ++m)
        #pragma unroll
        for (int j = 0; j < 4; ++j) {
          const float g = aG[tt][m][j];
          const float v = (g / (1.f + __expf(-g))) * aU[tt][m][j];
          U[swz(m*16 + rsub + j, col)] = f2b(v);
        }
    }
  }
  __syncthreads();

  // P5: Z = X + mid @ w_down^T (C-init from XT); k-outer; Z -> sN swz
  {
    f4v acc[3][4];
    #pragma unroll
    for (int t4 = 0; t4 < 4; ++t4) {
      const int col = wave*64 + t4*16 + l15;
      #pragma unroll
      for (int m = 0; m < 3; ++m) {
        const ushort4 xv = *(const ushort4*)&sXT[col*XTP + m*16 + rsub];
        acc[m][t4] = (f4v){b2f(xv.x), b2f(xv.y), b2f(xv.z), b2f(xv.w)};
      }
    }
    #pragma unroll
    for (int k = 0; k < 8; ++k) {
      bf8v aM[3];
      #pragma unroll
      for (int m = 0; m < 3; ++m)
        aM[m] = *(const bf8v*)(U + swz(m*16 + l15, k*32 + l16));
      #pragma unroll
      for (int t4 = 0; t4 < 4; ++t4) {
        const int col = wave*64 + t4*16 + l15;
        const bf8v b = wfrag<WBF16>(w_down, wbD, col, k*32 + l16);
        #pragma unroll
        for (int m = 0; m < 3; ++m)
          acc[m][t4] = mfma16(aM[m], b, acc[m][t4]);
      }
    }
    #pragma unroll
    for (int t4 = 0; t4 < 4; ++t4) {
      const int col = wave*64 + t4*16 + l15;
      #pragma unroll
      for (int m = 0; m < 3; ++m)
        #pragma unroll
        for (int j = 0; j < 4; ++j)
          sN[swz(m*16 + rsub + j, col)] = f2b(acc[m][t4][j]);
    }
  }
  __syncthreads();

  // P6: head GEMM on rows 1..32 + MSE vs gathered targets; k-outer
  float lsum = 0.f;
  {
    int cols[2]; f4v acc[2][2];
    #pragma unroll
    for (int t2 = 0; t2 < 2; ++t2) {
      cols[t2] = (wave*2 + t2)*16 + l15;   // 0..127
      const float bh = b_head[cols[t2]];
      acc[t2][0] = (f4v){bh,bh,bh,bh}; acc[t2][1] = acc[t2][0];
    }
    #pragma unroll
    for (int k = 0; k < 8; ++k) {
      bf8v aH[2];
      #pragma unroll
      for (int m = 0; m < 2; ++m)
        aH[m] = *(const bf8v*)(sN + swz(1 + m*16 + l15, k*32 + l16));
      #pragma unroll
      for (int t2 = 0; t2 < 2; ++t2) {
        const bf8v b = wfrag<WBF16>(w_head, wbH, cols[t2], k*32 + l16);
        #pragma unroll
        for (int m = 0; m < 2; ++m)
          acc[t2][m] = mfma16(aH[m], b, acc[t2][m]);
      }
    }
    #pragma unroll
    for (int t2 = 0; t2 < 2; ++t2)
      #pragma unroll
      for (int m = 0; m < 2; ++m)
        #pragma unroll
        for (int j = 0; j < 4; ++j) {
          const int row = 1 + m*16 + rsub + j;          // 1..32
          const float tv = target[(size_t)sIdx[row]*DOUT + cols[t2]];
          const float d = acc[t2][m][j] - tv;
          lsum += d*d;
        }
  }
  lsum = wred(lsum);
  if (lane == 0) sRed[wave] = lsum;
  __syncthreads();
  if (tid == 0)
    partial[bid] = (sRed[0]+sRed[1]+sRed[2]+sRed[3]) * (1.f/(DEG*DOUT));
}

// one-time (per launch) f32 -> bf16 weight conversion into d_ws
__global__ void cvt_w(const float* __restrict__ qkv, const float* __restrict__ o,
                      const float* __restrict__ g, const float* __restrict__ u,
                      const float* __restrict__ dn, const float* __restrict__ hd,
                      unsigned short* __restrict__ out)
{
  const int i = blockIdx.x*NTHREADS + threadIdx.x;
  const int e = i*2;
  if (e >= 491520) return;
  const float* src; int off;
  if      (e < 196608){ src=qkv; off=e; }
  else if (e < 262144){ src=o;  off=e-196608; }
  else if (e < 327680){ src=g;  off=e-262144; }
  else if (e < 393216){ src=u;  off=e-327680; }
  else if (e < 458752){ src=dn; off=e-393216; }
  else                { src=hd; off=e-458752; }
  const float2 v = *(const float2*)(src + off);
  const unsigned int pk = (unsigned int)f2b(v.x) | ((unsigned int)f2b(v.y) << 16);
  *(unsigned int*)(out + e) = pk;
}

__global__ void smtp_reduce(const float* __restrict__ partial, int B, float* __restrict__ out)
{
  __shared__ float sRed[4];
  const int tid = threadIdx.x;
  float s = 0.f;
  for (int i = tid; i < B; i += NTHREADS) s += partial[i];
  s = wred(s);
  if ((tid & 63) == 0) sRed[tid>>6] = s;
  __syncthreads();
  if (tid == 0) out[0] = (sRed[0]+sRed[1]+sRed[2]+sRed[3]) / (float)B;
}

extern "C" void kernel_launch(void* const* d_in, const int* in_sizes, int n_in,
                              void* d_out, int out_size, void* d_ws, size_t ws_size,
                              hipStream_t stream) {
  const float* H        = (const float*)d_in[0];
  const int*   edge     = (const int*)d_in[1];
  const int*   centers  = (const int*)d_in[2];
  const float* target   = (const float*)d_in[3];
  const float* ln_in_w  = (const float*)d_in[5];
  const float* ln1_w    = (const float*)d_in[6];
  const float* ln2_w    = (const float*)d_in[7];
  const float* w_qkv    = (const float*)d_in[8];
  const float* b_qkv    = (const float*)d_in[9];
  const float* w_o      = (const float*)d_in[10];
  const float* b_o      = (const float*)d_in[11];
  const float* w_gate   = (const float*)d_in[12];
  const float* w_up     = (const float*)d_in[13];
  const float* w_down   = (const float*)d_in[14];
  const float* w_head   = (const float*)d_in[15];
  const float* b_head   = (const float*)d_in[16];

  const int B = in_sizes[2];
  const int E = in_sizes[1] / 2;
  const int* dstE = edge + E;

  const size_t WB_ELEMS = 491520;
  const size_t NEED = WB_ELEMS*2 + (size_t)B*4;
  const bool useBf = (ws_size >= NEED);

  if (useBf) {
    unsigned short* wb = (unsigned short*)d_ws;
    float* partial = (float*)((char*)d_ws + WB_ELEMS*2);
    cvt_w<<<960, NTHREADS, 0, stream>>>(w_qkv, w_o, w_gate, w_up, w_down, w_head, wb);
    smtp_center<true><<<B, NTHREADS, 0, stream>>>(H, dstE, centers, target, ln_in_w, ln1_w, ln2_w,
        w_qkv, b_qkv, w_o, b_o, w_gate, w_up, w_down, w_head, b_head, wb, partial);
    smtp_reduce<<<1, NTHREADS, 0, stream>>>(partial, B, (float*)d_out);
  } else {
    float* partial = (float*)d_ws;
    smtp_center<false><<<B, NTHREADS, 0, stream>>>(H, dstE, centers, target, ln_in_w, ln1_w, ln2_w,
        w_qkv, b_qkv, w_o, b_o, w_gate, w_up, w_down, w_head, b_head, (const unsigned short*)d_ws, partial);
    smtp_reduce<<<1, NTHREADS, 0, stream>>>(partial, B, (float*)d_out);
  }
}